// Round 1
// baseline (112.371 us; speedup 1.0000x reference)
//
#include <hip/hip_runtime.h>

#define D_MODEL 768
#define BN 64
#define TILE_T 32
#define LN_EPS 1e-5f

typedef __attribute__((ext_vector_type(8))) short bf16x8;
typedef __attribute__((ext_vector_type(4))) float f32x4;

// RTNE float -> bf16 bits (no NaN special-case needed for this data)
static __device__ __forceinline__ unsigned short f2bf(float f) {
    unsigned int u = __float_as_uint(f);
    u = (u + 0x7FFFu + ((u >> 16) & 1u)) >> 16;
    return (unsigned short)u;
}

__global__ void prep_weights(const float* __restrict__ wd, const float* __restrict__ wu,
                             unsigned short* __restrict__ wd_b, unsigned short* __restrict__ wu_b) {
    int i = blockIdx.x * blockDim.x + threadIdx.x;
    if (i < BN * D_MODEL) {
        wd_b[i] = f2bf(wd[i]);
        wu_b[i] = f2bf(wu[i]);
    }
}

__global__ __launch_bounds__(256) void adapter_kernel(
    const float* __restrict__ x,
    const float* __restrict__ ln_w, const float* __restrict__ ln_b,
    const unsigned short* __restrict__ wd_b, const float* __restrict__ b_down,
    const unsigned short* __restrict__ wu_b, const float* __restrict__ b_up,
    float* __restrict__ out)
{
    // xn tile: stride 776 (768+8) -> row stride 388 dwords, 388%32=4 -> spread banks
    __shared__ __align__(16) unsigned short sXn[TILE_T][776];
    // down tile: stride 72 -> 36 dwords, 36%32=4
    __shared__ __align__(16) unsigned short sDown[TILE_T][72];

    const int tid  = threadIdx.x;
    const int lane = tid & 63;
    const int w    = tid >> 6;          // wave 0..3
    const int kg   = lane >> 4;         // k-group 0..3
    const int l16  = lane & 15;

    // ---------------- Phase 1: LayerNorm -> sXn (bf16) ----------------
    {
        const int token = tid >> 3;     // 0..31
        const int part  = tid & 7;      // 0..7, 96 floats each
        const float* xrow = x + (size_t)(blockIdx.x * TILE_T + token) * D_MODEL;
        const float4* xv = ((const float4*)xrow) + part * 24;
        float sum = 0.f, sq = 0.f;
        #pragma unroll
        for (int i = 0; i < 24; ++i) {
            float4 v = xv[i];
            sum += v.x + v.y + v.z + v.w;
            sq  += v.x*v.x + v.y*v.y + v.z*v.z + v.w*v.w;
        }
        #pragma unroll
        for (int off = 1; off < 8; off <<= 1) {
            sum += __shfl_xor(sum, off);
            sq  += __shfl_xor(sq, off);
        }
        const float mean = sum * (1.f / D_MODEL);
        const float var  = sq * (1.f / D_MODEL) - mean * mean;
        const float rstd = rsqrtf(var + LN_EPS);
        const float4* wv = ((const float4*)ln_w) + part * 24;
        const float4* bv = ((const float4*)ln_b) + part * 24;
        const int cbase = part * 96;
        #pragma unroll
        for (int i = 0; i < 24; ++i) {
            float4 v = xv[i], g = wv[i], b = bv[i];
            ushort4 o;
            o.x = f2bf((v.x - mean) * rstd * g.x + b.x);
            o.y = f2bf((v.y - mean) * rstd * g.y + b.y);
            o.z = f2bf((v.z - mean) * rstd * g.z + b.z);
            o.w = f2bf((v.w - mean) * rstd * g.w + b.w);
            *(ushort4*)&sXn[token][cbase + 4*i] = o;
        }
    }
    __syncthreads();

    // ---------------- Phase 2: down = relu(xn @ wd^T + b_down) -> sDown ----------------
    {
        const int rowBase = (w & 1) * 16;       // token-half
        const int colBase = (w >> 1) * 32;      // 2 N-tiles of 16
        const int arow = rowBase + l16;
        f32x4 acc0 = {0.f,0.f,0.f,0.f}, acc1 = {0.f,0.f,0.f,0.f};
        const unsigned short* b0p = wd_b + (size_t)(colBase + l16) * D_MODEL + kg * 8;
        const unsigned short* b1p = b0p + 16 * D_MODEL;
        #pragma unroll
        for (int ks = 0; ks < D_MODEL / 32; ++ks) {
            const int k0 = ks * 32;
            bf16x8 a  = *(const bf16x8*)&sXn[arow][k0 + kg * 8];
            bf16x8 b0 = *(const bf16x8*)(b0p + k0);
            bf16x8 b1 = *(const bf16x8*)(b1p + k0);
            acc0 = __builtin_amdgcn_mfma_f32_16x16x32_bf16(a, b0, acc0, 0, 0, 0);
            acc1 = __builtin_amdgcn_mfma_f32_16x16x32_bf16(a, b1, acc1, 0, 0, 0);
        }
        // D layout: col = lane&15, row = (lane>>4)*4 + r
        const int trowB = rowBase + kg * 4;
        const int c0 = colBase + l16;
        const float bd0 = b_down[c0], bd1 = b_down[c0 + 16];
        #pragma unroll
        for (int r = 0; r < 4; ++r) {
            float v0 = acc0[r] + bd0; v0 = v0 > 0.f ? v0 : 0.f;
            float v1 = acc1[r] + bd1; v1 = v1 > 0.f ? v1 : 0.f;
            sDown[trowB + r][c0]      = f2bf(v0);
            sDown[trowB + r][c0 + 16] = f2bf(v1);
        }
    }
    __syncthreads();

    // ---------------- Phase 3: out = down @ wu^T + b_up + x ----------------
    {
        const int rowBase = (w & 1) * 16;
        const int arow = rowBase + l16;
        // Preload full A strip for this row-half: K=64 -> 2 frags
        bf16x8 a0 = *(const bf16x8*)&sDown[arow][kg * 8];
        bf16x8 a1 = *(const bf16x8*)&sDown[arow][32 + kg * 8];
        const int trowB = rowBase + kg * 4;
        const size_t gt0 = (size_t)blockIdx.x * TILE_T;
        // 48 col-tiles total; wave-pair (w>>1) takes every other tile
        for (int j = 0; j < 24; ++j) {
            const int colBase = ((w >> 1) + 2 * j) * 16;
            const int bcol = colBase + l16;
            bf16x8 b0 = *(const bf16x8*)(wu_b + (size_t)bcol * BN + kg * 8);
            bf16x8 b1 = *(const bf16x8*)(wu_b + (size_t)bcol * BN + 32 + kg * 8);
            f32x4 acc = {0.f,0.f,0.f,0.f};
            acc = __builtin_amdgcn_mfma_f32_16x16x32_bf16(a0, b0, acc, 0, 0, 0);
            acc = __builtin_amdgcn_mfma_f32_16x16x32_bf16(a1, b1, acc, 0, 0, 0);
            const float bu = b_up[bcol];
            #pragma unroll
            for (int r = 0; r < 4; ++r) {
                const size_t row = gt0 + (size_t)(trowB + r);
                const size_t idx = row * D_MODEL + bcol;
                out[idx] = acc[r] + bu + x[idx];   // SCALE == 1.0
            }
        }
    }
}

extern "C" void kernel_launch(void* const* d_in, const int* in_sizes, int n_in,
                              void* d_out, int out_size, void* d_ws, size_t ws_size,
                              hipStream_t stream) {
    const float* x      = (const float*)d_in[0];
    const float* ln_w   = (const float*)d_in[1];
    const float* ln_b   = (const float*)d_in[2];
    const float* w_down = (const float*)d_in[3];
    const float* b_down = (const float*)d_in[4];
    const float* w_up   = (const float*)d_in[5];
    const float* b_up   = (const float*)d_in[6];
    float* out = (float*)d_out;

    unsigned short* wd_b = (unsigned short*)d_ws;
    unsigned short* wu_b = wd_b + BN * D_MODEL;

    prep_weights<<<(BN * D_MODEL + 255) / 256, 256, 0, stream>>>(w_down, w_up, wd_b, wu_b);

    const int tokens = in_sizes[0] / D_MODEL;   // 32768
    const int grid = tokens / TILE_T;           // 1024
    adapter_kernel<<<grid, 256, 0, stream>>>(x, ln_w, ln_b, wd_b, b_down, wu_b, b_up, out);
}

// Round 2
// 80.236 us; speedup vs baseline: 1.4005x; 1.4005x over previous
//
#include <hip/hip_runtime.h>

#define D_MODEL 768
#define BN 64
#define TILE_T 16
#define LN_EPS 1e-5f

typedef __attribute__((ext_vector_type(8))) short bf16x8;
typedef __attribute__((ext_vector_type(4))) float f32x4;

// RTNE float -> bf16 bits
static __device__ __forceinline__ unsigned short f2bf(float f) {
    unsigned int u = __float_as_uint(f);
    u = (u + 0x7FFFu + ((u >> 16) & 1u)) >> 16;
    return (unsigned short)u;
}
static __device__ __forceinline__ float bf2f(unsigned short u) {
    return __uint_as_float(((unsigned int)u) << 16);
}

// Fold LayerNorm affine into the down-projection:
//   wd2[k,d] = wd[k,d] * ln_w[d]          (bf16)
//   S[k]     = sum_d wd2[k,d]             (f32)
//   bd2[k]   = b_down[k] + sum_d wd[k,d]*ln_b[d]
// Then down_pre[t,k] = rstd[t]*(x_bf[t,:]@wd2[k,:] - mu[t]*S[k]) + bd2[k]
__global__ void prep(const float* __restrict__ wd, const float* __restrict__ ln_w,
                     const float* __restrict__ ln_b, const float* __restrict__ b_down,
                     const float* __restrict__ wu,
                     unsigned short* __restrict__ wd2_b, unsigned short* __restrict__ wu_b,
                     float* __restrict__ S, float* __restrict__ bd2) {
    const int k = blockIdx.x;    // 0..63
    const int t = threadIdx.x;   // 0..63
    float s = 0.f, sb = 0.f;
    #pragma unroll
    for (int i = 0; i < 12; ++i) {
        const int d = t + 64 * i;
        const float w0 = wd[k * D_MODEL + d];
        const float w2 = w0 * ln_w[d];
        wd2_b[k * D_MODEL + d] = f2bf(w2);
        s  += w2;
        sb += w0 * ln_b[d];
    }
    #pragma unroll
    for (int off = 1; off < 64; off <<= 1) {
        s  += __shfl_xor(s, off);
        sb += __shfl_xor(sb, off);
    }
    if (t == 0) { S[k] = s; bd2[k] = b_down[k] + sb; }
    // convert up-projection weights (wu is [768][64] row-major)
    #pragma unroll
    for (int i = 0; i < 12; ++i) {
        const int idx = (k * 12 + i) * BN + t;
        wu_b[idx] = f2bf(wu[idx]);
    }
}

__global__ __launch_bounds__(256, 6) void adapter_kernel(
    const float* __restrict__ x,
    const unsigned short* __restrict__ wd2_b, const float* __restrict__ S,
    const float* __restrict__ bd2,
    const unsigned short* __restrict__ wu_b, const float* __restrict__ b_up,
    float* __restrict__ out)
{
    // raw x (bf16) tile; stride 776 shorts = 1552 B (16B-aligned rows, 4-dword bank skew)
    __shared__ __align__(16) unsigned short sX[TILE_T][776];
    __shared__ float sMu[TILE_T];
    __shared__ float sRstd[TILE_T];

    const int tid  = threadIdx.x;
    const int lane = tid & 63;
    const int w    = tid >> 6;       // wave 0..3
    const int kg   = lane >> 4;      // 0..3
    const int l16  = lane & 15;
    const size_t gt0 = (size_t)blockIdx.x * TILE_T;

    // ---------- Phase 1: load x, stats, store raw bf16 x ----------
    {
        const int token = tid >> 4;  // 0..15
        const int part  = tid & 15;  // 0..15
        const float4* xv = (const float4*)(x + (gt0 + token) * D_MODEL);
        float sum = 0.f, sq = 0.f;
        #pragma unroll
        for (int i = 0; i < 12; ++i) {
            const float4 v = xv[i * 16 + part];
            sum += v.x + v.y + v.z + v.w;
            sq  += v.x * v.x + v.y * v.y + v.z * v.z + v.w * v.w;
            ushort4 o;
            o.x = f2bf(v.x); o.y = f2bf(v.y); o.z = f2bf(v.z); o.w = f2bf(v.w);
            *(ushort4*)&sX[token][(i * 16 + part) * 4] = o;
        }
        #pragma unroll
        for (int off = 1; off < 16; off <<= 1) {
            sum += __shfl_xor(sum, off);
            sq  += __shfl_xor(sq, off);
        }
        if (part == 0) {
            const float mean = sum * (1.f / D_MODEL);
            const float var  = sq * (1.f / D_MODEL) - mean * mean;
            sMu[token]   = mean;
            sRstd[token] = rsqrtf(var + LN_EPS);
        }
    }
    __syncthreads();

    // ---------- Phase 2: G = x_bf @ wd2^T ; down = relu(rstd*(G - mu*S) + bd2) ----------
    unsigned short dv[4];
    {
        const int c = w * 16 + l16;          // 0..63
        f32x4 acc = {0.f, 0.f, 0.f, 0.f};
        const unsigned short* bp = wd2_b + (size_t)c * D_MODEL + kg * 8;
        #pragma unroll
        for (int ks = 0; ks < D_MODEL / 32; ++ks) {
            bf16x8 a = *(const bf16x8*)&sX[l16][ks * 32 + kg * 8];
            bf16x8 b = *(const bf16x8*)(bp + ks * 32);
            acc = __builtin_amdgcn_mfma_f32_16x16x32_bf16(a, b, acc, 0, 0, 0);
        }
        const float Sc = S[c], bd = bd2[c];
        #pragma unroll
        for (int r = 0; r < 4; ++r) {
            const int row = kg * 4 + r;
            float v = sRstd[row] * (acc[r] - sMu[row] * Sc) + bd;
            dv[r] = f2bf(v > 0.f ? v : 0.f);
        }
    }
    __syncthreads();   // everyone done reading sX -> safe to alias
    {
        unsigned short (*sDown)[72] = (unsigned short (*)[72])&sX[0][0];
        const int c = w * 16 + l16;
        #pragma unroll
        for (int r = 0; r < 4; ++r) sDown[kg * 4 + r][c] = dv[r];
    }
    __syncthreads();

    // ---------- Phase 3: out = down @ wu^T + b_up + x ----------
    {
        unsigned short (*sDown)[72] = (unsigned short (*)[72])&sX[0][0];
        const bf16x8 a0 = *(const bf16x8*)&sDown[l16][kg * 8];
        const bf16x8 a1 = *(const bf16x8*)&sDown[l16][32 + kg * 8];
        #pragma unroll
        for (int j = 0; j < 12; ++j) {
            const int bcol = (w + 4 * j) * 16 + l16;
            const unsigned short* wp = wu_b + (size_t)bcol * BN;
            const bf16x8 b0 = *(const bf16x8*)(wp + kg * 8);
            const bf16x8 b1 = *(const bf16x8*)(wp + 32 + kg * 8);
            f32x4 acc = {0.f, 0.f, 0.f, 0.f};
            acc = __builtin_amdgcn_mfma_f32_16x16x32_bf16(a0, b0, acc, 0, 0, 0);
            acc = __builtin_amdgcn_mfma_f32_16x16x32_bf16(a1, b1, acc, 0, 0, 0);
            const float bu = b_up[bcol];
            #pragma unroll
            for (int r = 0; r < 4; ++r) {
                const int row = kg * 4 + r;
                const size_t idx = (gt0 + row) * D_MODEL + bcol;
                out[idx] = acc[r] + bu + x[idx];   // SCALE == 1.0, exact fp32 residual
            }
        }
    }
}

extern "C" void kernel_launch(void* const* d_in, const int* in_sizes, int n_in,
                              void* d_out, int out_size, void* d_ws, size_t ws_size,
                              hipStream_t stream) {
    const float* x      = (const float*)d_in[0];
    const float* ln_w   = (const float*)d_in[1];
    const float* ln_b   = (const float*)d_in[2];
    const float* w_down = (const float*)d_in[3];
    const float* b_down = (const float*)d_in[4];
    const float* w_up   = (const float*)d_in[5];
    const float* b_up   = (const float*)d_in[6];
    float* out = (float*)d_out;

    unsigned short* wd2_b = (unsigned short*)d_ws;               // 64*768 ush
    unsigned short* wu_b  = wd2_b + BN * D_MODEL;                // 768*64 ush
    float* S   = (float*)((char*)d_ws + 2 * BN * D_MODEL * sizeof(unsigned short));
    float* bd2 = S + BN;

    prep<<<BN, 64, 0, stream>>>(w_down, ln_w, ln_b, b_down, w_up, wd2_b, wu_b, S, bd2);

    const int tokens = in_sizes[0] / D_MODEL;   // 32768
    const int grid = tokens / TILE_T;           // 2048
    adapter_kernel<<<grid, 256, 0, stream>>>(x, wd2_b, S, bd2, wu_b, b_up, out);
}